// Round 5
// baseline (193.227 us; speedup 1.0000x reference)
//
#include <hip/hip_runtime.h>
#include <hip/hip_bf16.h>

// SkeletonLinear: out[b, 32d+n] = sum_k x[b,k] * W[32d+n, k] + bias[32d+n],
// k over [32(d-1), 32(d+1)) for d>=1, [0,32) for d=0 (block-bidiagonal mask).
//
// R5: zero-barrier streaming. One wave = 16-row strip x 6 nodes, fully
// independent (wave-private LDS, s_waitcnt-only ordering):
//   - rolling 4-slot bf16 x-chunk ring (32 cols/chunk), staged 2-3 nodes
//     ahead -> compiler software-pipelines the unrolled loop like a copy
//     kernel (loads always in flight, never a vmcnt(0)+barrier drain).
//   - A-frag = one ds_read_b128; B = prepacked bf16 fragments (coalesced).
//   - out panel in LDS converts MFMA col-layout -> 2 coalesced dwordx4
//     stores per node (vs 8 scattered dword stores).

typedef __bf16 bf16x4 __attribute__((ext_vector_type(4)));
typedef __bf16 bf16x8 __attribute__((ext_vector_type(8)));
typedef float  f32x4  __attribute__((ext_vector_type(4)));

#define DIM 768
#define XPAD 40               // bf16/row in x slot (32+8): 16B-aligned rows, uniform banks
#define XSLOT (16 * XPAD)     // 640 bf16 = 1280 B per slot
#define OPAD 36               // fp32/row in out panel (32+4): 16B-aligned rows

__device__ __forceinline__ bf16x8 cvt8(const float* __restrict__ p) {
    float4 lo = *(const float4*)p;
    float4 hi = *(const float4*)(p + 4);
    bf16x8 r;
    r[0] = (__bf16)lo.x; r[1] = (__bf16)lo.y; r[2] = (__bf16)lo.z; r[3] = (__bf16)lo.w;
    r[4] = (__bf16)hi.x; r[5] = (__bf16)hi.y; r[6] = (__bf16)hi.z; r[7] = (__bf16)hi.w;
    return r;
}

// ---- Prepack: W (fp32) -> bf16 B-fragments, fragment-ordered.
// fid = ((d*2+kt)*2+ni)*64 + lane; lane holds B[k=8*quad+j][n=16ni+l16]
// = W[32d+16ni+l16][32(d-1)+32kt+8*quad+j]; d==0,kt==0 -> zeros.
__global__ void prepack_w_kernel(const float* __restrict__ w, bf16x8* __restrict__ ws)
{
    const int fid = blockIdx.x * 256 + threadIdx.x;   // 0..6143
    const int lane = fid & 63;
    const int ni   = (fid >> 6) & 1;
    const int kt   = (fid >> 7) & 1;
    const int d    = fid >> 8;
    const int quad = lane >> 4, l16 = lane & 15;

    bf16x8 v;
    if (d == 0 && kt == 0) {
#pragma unroll
        for (int j = 0; j < 8; ++j) v[j] = (__bf16)0.f;
    } else {
        const float* src = w + (long)(32 * d + 16 * ni + l16) * DIM
                             + (32 * d - 32 + 32 * kt + 8 * quad);
        v = cvt8(src);
    }
    ws[fid] = v;
}

__global__ __launch_bounds__(256, 4)
void skeleton_linear_kernel(const float* __restrict__ x,
                            const float* __restrict__ bias,
                            const bf16x8* __restrict__ wfrag,
                            float* __restrict__ out)
{
    // wave-private regions; NO __syncthreads in this kernel.
    __shared__ __align__(16) __bf16 xs[4][4 * XSLOT];   // 4 waves x 4-slot ring
    __shared__ __align__(16) float  os[4][16 * OPAD];   // 4 waves x out panel

    const int tid  = threadIdx.x;
    const int lane = tid & 63;
    const int wave = tid >> 6;
    const int quad = lane >> 4;
    const int l16  = lane & 15;
    const int d0   = wave * 6;                 // this wave's first node
    const long row0 = (long)blockIdx.x * 16;   // 16-row strip

    __bf16* __restrict__ xw = xs[wave];
    float*  __restrict__ ow = os[wave];

    // staging lane map: rows srow & srow+8, 16B column chunk sc4
    const int srow = lane >> 3;                // 0..7
    const int sc4  = lane & 7;                 // 0..7
    const float* xbase = x + (row0 + srow) * DIM + 4 * sc4;

    // stage 32-col chunk c into ring slot s (2 coalesced dwordx4, 8x128B segs)
    auto stage = [&](int c, int s) {
        const float* src = xbase + 32 * c;
        float4 v0 = *(const float4*)src;
        float4 v1 = *(const float4*)(src + 8 * DIM);
        bf16x4 b0, b1;
        b0[0] = (__bf16)v0.x; b0[1] = (__bf16)v0.y; b0[2] = (__bf16)v0.z; b0[3] = (__bf16)v0.w;
        b1[0] = (__bf16)v1.x; b1[1] = (__bf16)v1.y; b1[2] = (__bf16)v1.z; b1[3] = (__bf16)v1.w;
        __bf16* dst = xw + s * XSLOT + srow * XPAD + 4 * sc4;
        *(bf16x4*)dst = b0;
        *(bf16x4*)(dst + 8 * XPAD) = b1;
    };

    // preload chunks j=0,1,2 (chunk j covers cols 32*(d0-1+j))
    stage(d0 > 0 ? d0 - 1 : 0, 0);   // parent of node d0 (clamped; unused for d=0)
    stage(d0, 1);
    stage(d0 + 1, 2);

#pragma unroll
    for (int i = 0; i < 6; ++i) {
        const int d = d0 + i;
        if (i < 4) stage(d0 + i + 2, (i + 3) & 3);   // keep 2-3 chunks in flight

        const int fb = 4 * d;
        f32x4 a0 = {0.f, 0.f, 0.f, 0.f};
        f32x4 a1 = {0.f, 0.f, 0.f, 0.f};

        if (d > 0) {   // parent chunk: ring slot i&3 (A[m=l16][k=8q+j], verified)
            bf16x8 ap = *(const bf16x8*)(xw + (i & 3) * XSLOT + l16 * XPAD + 8 * quad);
            a0 = __builtin_amdgcn_mfma_f32_16x16x32_bf16(ap, wfrag[(fb + 0) * 64 + lane], a0, 0, 0, 0);
            a1 = __builtin_amdgcn_mfma_f32_16x16x32_bf16(ap, wfrag[(fb + 1) * 64 + lane], a1, 0, 0, 0);
        }
        {              // self chunk: ring slot (i+1)&3
            bf16x8 as = *(const bf16x8*)(xw + ((i + 1) & 3) * XSLOT + l16 * XPAD + 8 * quad);
            a0 = __builtin_amdgcn_mfma_f32_16x16x32_bf16(as, wfrag[(fb + 2) * 64 + lane], a0, 0, 0, 0);
            a1 = __builtin_amdgcn_mfma_f32_16x16x32_bf16(as, wfrag[(fb + 3) * 64 + lane], a1, 0, 0, 0);
        }

        // bias + out panel (C/D: col=l16, row=4*quad+reg; 2-way banks = free)
        const float bi0 = bias[32 * d + l16];
        const float bi1 = bias[32 * d + 16 + l16];
#pragma unroll
        for (int r = 0; r < 4; ++r) {
            ow[(4 * quad + r) * OPAD + l16]      = a0[r] + bi0;
            ow[(4 * quad + r) * OPAD + 16 + l16] = a1[r] + bi1;
        }
        // coalesced read-back + 2 dwordx4 global stores (8x128B segments)
        float4 o0 = *(const float4*)(ow + srow * OPAD + 4 * sc4);
        float4 o1 = *(const float4*)(ow + (srow + 8) * OPAD + 4 * sc4);
        float* gdst = out + (row0 + srow) * DIM + 32 * d + 4 * sc4;
        *(float4*)gdst = o0;
        *(float4*)(gdst + 8 * DIM) = o1;
    }
}

extern "C" void kernel_launch(void* const* d_in, const int* in_sizes, int n_in,
                              void* d_out, int out_size, void* d_ws, size_t ws_size,
                              hipStream_t stream) {
    const float* x    = (const float*)d_in[0];   // [32768, 768] fp32
    const float* w    = (const float*)d_in[1];   // [768, 768] fp32
    const float* bias = (const float*)d_in[2];   // [768] fp32
    // d_in[3] = mask: structure hard-coded (mask==1 inside used blocks).
    float* out = (float*)d_out;                  // [32768, 768] fp32

    bf16x8* wpack = (bf16x8*)d_ws;               // 96 frags * 1 KB = 96 KB

    prepack_w_kernel<<<24, 256, 0, stream>>>(w, wpack);

    const int BATCH = 32768;
    dim3 grid(BATCH / 16);                       // 2048 blocks x 256 thr (4 waves)
    skeleton_linear_kernel<<<grid, 256, 0, stream>>>(x, bias, wpack, out);
}